// Round 1
// baseline (651.103 us; speedup 1.0000x reference)
//
#include <hip/hip_runtime.h>

typedef float v4f __attribute__((ext_vector_type(4)));

#define N_NODES_C 50000
#define N_EDGES_C 800000
#define NF 128
#define N_GRAPHS_C 256
#define N_CLASSES_C 10

// ---------------------------------------------------------------- CSR build
__global__ void k_deg(const int* __restrict__ dst, int* __restrict__ deg) {
  int i = blockIdx.x * blockDim.x + threadIdx.x;
  int stride = gridDim.x * blockDim.x;
  for (; i < N_EDGES_C; i += stride) atomicAdd(&deg[dst[i]], 1);
}

__global__ void k_dinv(const int* __restrict__ deg, float* __restrict__ dinv) {
  int i = blockIdx.x * blockDim.x + threadIdx.x;
  if (i < N_NODES_C) dinv[i] = 1.0f / sqrtf((float)deg[i] + 1.0f);
}

__global__ __launch_bounds__(1024) void k_scan(const int* __restrict__ deg,
                                               int* __restrict__ ptr) {
  __shared__ int sd[1024];
  int t = threadIdx.x;
  const int n = N_NODES_C;
  int per = (n + 1023) >> 10;           // 49
  int beg = t * per;
  int end = min(beg + per, n);
  int s = 0;
  for (int i = beg; i < end; ++i) s += deg[i];
  sd[t] = s;
  __syncthreads();
  for (int o = 1; o < 1024; o <<= 1) {
    int y = (t >= o) ? sd[t - o] : 0;
    __syncthreads();
    sd[t] += y;
    __syncthreads();
  }
  int run = (t > 0) ? sd[t - 1] : 0;
  for (int i = beg; i < end; ++i) { ptr[i] = run; run += deg[i]; }
  if (t == 1023) ptr[n] = sd[1023];
}

__global__ void k_fill(const int* __restrict__ src, const int* __restrict__ dst,
                       const int* __restrict__ ptr, int* __restrict__ fill,
                       int* __restrict__ csr_src) {
  int i = blockIdx.x * blockDim.x + threadIdx.x;
  int stride = gridDim.x * blockDim.x;
  for (; i < N_EDGES_C; i += stride) {
    int d = dst[i];
    int pos = atomicAdd(&fill[d], 1);
    csr_src[ptr[d] + pos] = src[i];
  }
}

// ---------------------------------------------------------------- GEMM (fp32 vector)
// out[n][128] = A[n][128] @ W[128][128]; fuse=1 -> relu(out + bias)
#define TN 64
__global__ __launch_bounds__(256) void k_gemm(const float* __restrict__ A,
    const float* __restrict__ W, const float* __restrict__ bias,
    float* __restrict__ out, int n, int fuse) {
  __shared__ float Wl[64 * 128];   // 32 KB: W rows kk..kk+63
  __shared__ float Hl[TN * 128];   // 32 KB
  int t = threadIdx.x;
  int oq = t & 15;          // outputs 8*oq .. 8*oq+7
  int ng4 = (t >> 4) * 4;   // local nodes ng4..ng4+3
  int nchunks = (n + TN - 1) / TN;
  for (int chunk = blockIdx.x; chunk < nchunks; chunk += gridDim.x) {
    int n0 = chunk * TN;
    __syncthreads();
    {
      const v4f* A4 = (const v4f*)A;
      v4f* H4 = (v4f*)Hl;
      #pragma unroll
      for (int i = 0; i < 8; ++i) {
        int idx = t + i * 256;              // float4 index in tile
        int row = n0 + (idx >> 5);
        H4[idx] = (row < n) ? A4[(size_t)row * 32 + (idx & 31)] : (v4f)0.0f;
      }
    }
    v4f acc0[4], acc1[4];
    #pragma unroll
    for (int j = 0; j < 4; ++j) { acc0[j] = (v4f)0.0f; acc1[j] = (v4f)0.0f; }
    #pragma unroll 1
    for (int half = 0; half < 2; ++half) {
      int kk = half << 6;
      __syncthreads();
      {
        const v4f* W4 = (const v4f*)(W + (size_t)kk * 128);
        v4f* WL4 = (v4f*)Wl;
        #pragma unroll
        for (int i = 0; i < 8; ++i) WL4[t + i * 256] = W4[t + i * 256];
      }
      __syncthreads();
      #pragma unroll 4
      for (int k4 = 0; k4 < 16; ++k4) {
        v4f hA = *(const v4f*)&Hl[(ng4 + 0) * 128 + kk + k4 * 4];
        v4f hB = *(const v4f*)&Hl[(ng4 + 1) * 128 + kk + k4 * 4];
        v4f hC = *(const v4f*)&Hl[(ng4 + 2) * 128 + kk + k4 * 4];
        v4f hD = *(const v4f*)&Hl[(ng4 + 3) * 128 + kk + k4 * 4];
        #pragma unroll
        for (int u = 0; u < 4; ++u) {
          const float* wr = Wl + (k4 * 4 + u) * 128 + oq * 8;
          v4f w0 = *(const v4f*)wr;
          v4f w1 = *(const v4f*)(wr + 4);
          acc0[0] += hA[u] * w0; acc1[0] += hA[u] * w1;
          acc0[1] += hB[u] * w0; acc1[1] += hB[u] * w1;
          acc0[2] += hC[u] * w0; acc1[2] += hC[u] * w1;
          acc0[3] += hD[u] * w0; acc1[3] += hD[u] * w1;
        }
      }
    }
    v4f b0 = (v4f)0.0f, b1 = (v4f)0.0f;
    if (fuse) { b0 = *(const v4f*)(bias + oq * 8); b1 = *(const v4f*)(bias + oq * 8 + 4); }
    #pragma unroll
    for (int j = 0; j < 4; ++j) {
      int row = n0 + ng4 + j;
      if (row >= n) break;
      v4f r0 = acc0[j], r1 = acc1[j];
      if (fuse) {
        r0 += b0; r1 += b1;
        #pragma unroll
        for (int c = 0; c < 4; ++c) { r0[c] = fmaxf(r0[c], 0.0f); r1[c] = fmaxf(r1[c], 0.0f); }
      }
      *(v4f*)(out + (size_t)row * 128 + oq * 8) = r0;
      *(v4f*)(out + (size_t)row * 128 + oq * 8 + 4) = r1;
    }
  }
}

// ---------------------------------------------------------------- aggregation
// h[i] = relu(dinv_i * sum_{j->i} dinv_j*hw_j + dinv_i^2*hw_i + b) (+ h[i] if residual)
__global__ __launch_bounds__(256) void k_agg(const float* __restrict__ hw,
    const int* __restrict__ ptr, const int* __restrict__ csr_src,
    const float* __restrict__ dinv, const float* __restrict__ bias,
    float* __restrict__ h, int residual) {
  int node = blockIdx.x * 4 + (threadIdx.x >> 6);
  int lane = threadIdx.x & 63;
  if (node >= N_NODES_C) return;
  const float2* hw2 = (const float2*)hw;
  int beg = ptr[node], end = ptr[node + 1];
  float ax = 0.f, ay = 0.f;
  int e = beg;
  for (; e + 4 <= end; e += 4) {
    int s0 = csr_src[e], s1 = csr_src[e + 1], s2 = csr_src[e + 2], s3 = csr_src[e + 3];
    float d0 = dinv[s0], d1 = dinv[s1], d2 = dinv[s2], d3 = dinv[s3];
    float2 v0 = hw2[s0 * 64 + lane];
    float2 v1 = hw2[s1 * 64 + lane];
    float2 v2 = hw2[s2 * 64 + lane];
    float2 v3 = hw2[s3 * 64 + lane];
    ax += d0 * v0.x + d1 * v1.x + d2 * v2.x + d3 * v3.x;
    ay += d0 * v0.y + d1 * v1.y + d2 * v2.y + d3 * v3.y;
  }
  for (; e < end; ++e) {
    int s = csr_src[e];
    float d = dinv[s];
    float2 v = hw2[s * 64 + lane];
    ax += d * v.x; ay += d * v.y;
  }
  float di = dinv[node];
  float2 self = hw2[node * 64 + lane];
  float2 b = ((const float2*)bias)[lane];
  float vx = fmaxf(di * ax + di * di * self.x + b.x, 0.0f);
  float vy = fmaxf(di * ay + di * di * self.y + b.y, 0.0f);
  float2* h2 = (float2*)h;
  if (residual) {
    float2 old = h2[node * 64 + lane];
    vx += old.x; vy += old.y;
  }
  h2[node * 64 + lane] = make_float2(vx, vy);
}

// ---------------------------------------------------------------- pooling + head
__global__ void k_bounds(const int* __restrict__ batch, int* __restrict__ gstart) {
  int g = threadIdx.x;
  if (g > N_GRAPHS_C) return;
  int lo = 0, hi = N_NODES_C;
  while (lo < hi) {
    int mid = (lo + hi) >> 1;
    if (batch[mid] < g) lo = mid + 1; else hi = mid;
  }
  gstart[g] = lo;
}

__global__ void k_pool(const float* __restrict__ h, const int* __restrict__ gstart,
                       float* __restrict__ gpool) {
  int g = blockIdx.x;
  int f = threadIdx.x;    // 128 threads
  int beg = gstart[g], end = gstart[g + 1];
  float acc = 0.f;
  for (int n2 = beg; n2 < end; ++n2) acc += h[(size_t)n2 * NF + f];
  float cnt = (float)(end - beg);
  gpool[g * NF + f] = acc / fmaxf(cnt, 1.0f);
}

__global__ void k_head(const float* __restrict__ gpool, const float* __restrict__ Wc1,
                       const float* __restrict__ bc1, const float* __restrict__ Wc2,
                       const float* __restrict__ bc2, float* __restrict__ out) {
  __shared__ float gv[128];
  __shared__ float hid[64];
  int g = blockIdx.x, t = threadIdx.x;   // 64 threads
  gv[t] = gpool[g * 128 + t];
  gv[t + 64] = gpool[g * 128 + t + 64];
  __syncthreads();
  float s = bc1[t];
  #pragma unroll 8
  for (int k = 0; k < 128; ++k) s += gv[k] * Wc1[k * 64 + t];
  hid[t] = fmaxf(s, 0.0f);
  __syncthreads();
  if (t < N_CLASSES_C) {
    float o = bc2[t];
    #pragma unroll
    for (int k = 0; k < 64; ++k) o += hid[k] * Wc2[k * 10 + t];
    out[g * 10 + t] = o;
  }
}

// ---------------------------------------------------------------- launch
extern "C" void kernel_launch(void* const* d_in, const int* in_sizes, int n_in,
                              void* d_out, int out_size, void* d_ws, size_t ws_size,
                              hipStream_t stream) {
  const float* x    = (const float*)d_in[0];
  const int*   ei   = (const int*)d_in[1];
  const int*   batch= (const int*)d_in[2];
  const float* W_in = (const float*)d_in[3];
  const float* b_in = (const float*)d_in[4];
  const float* Ws   = (const float*)d_in[5];
  const float* bs   = (const float*)d_in[6];
  const float* Wc1  = (const float*)d_in[7];
  const float* bc1  = (const float*)d_in[8];
  const float* Wc2  = (const float*)d_in[9];
  const float* bc2  = (const float*)d_in[10];
  float* out = (float*)d_out;

  const int* src = ei;               // row 0
  const int* dst = ei + N_EDGES_C;   // row 1

  char* ws = (char*)d_ws;
  size_t off = 0;
  auto alloc = [&](size_t bytes) -> void* {
    void* p = ws + off;
    off += (bytes + 255) & ~(size_t)255;
    return p;
  };
  int*   deg     = (int*)alloc(N_NODES_C * 4);
  int*   fill    = (int*)alloc(N_NODES_C * 4);
  int*   csr_ptr = (int*)alloc((N_NODES_C + 1) * 4);
  int*   csr_src = (int*)alloc((size_t)N_EDGES_C * 4);
  float* dinv    = (float*)alloc(N_NODES_C * 4);
  int*   gstart  = (int*)alloc((N_GRAPHS_C + 1) * 4);
  float* h       = (float*)alloc((size_t)N_NODES_C * NF * 4);
  float* hw      = (float*)alloc((size_t)N_NODES_C * NF * 4);
  float* gpool   = (float*)alloc((size_t)N_GRAPHS_C * NF * 4);
  (void)ws_size; (void)in_sizes; (void)n_in; (void)out_size;

  hipMemsetAsync(deg, 0, N_NODES_C * 4, stream);
  hipMemsetAsync(fill, 0, N_NODES_C * 4, stream);

  k_deg <<<1024, 256, 0, stream>>>(dst, deg);
  k_dinv<<<(N_NODES_C + 255) / 256, 256, 0, stream>>>(deg, dinv);
  k_scan<<<1, 1024, 0, stream>>>(deg, csr_ptr);
  k_fill<<<1024, 256, 0, stream>>>(src, dst, csr_ptr, fill, csr_src);

  // input layer: h = relu(x @ W_in + b_in)
  k_gemm<<<512, 256, 0, stream>>>(x, W_in, b_in, h, N_NODES_C, 1);

  for (int L = 0; L < 3; ++L) {
    k_gemm<<<512, 256, 0, stream>>>(h, Ws + (size_t)L * NF * NF, nullptr, hw, N_NODES_C, 0);
    k_agg <<<(N_NODES_C + 3) / 4, 256, 0, stream>>>(hw, csr_ptr, csr_src, dinv,
                                                    bs + (size_t)L * NF, h, (L > 0) ? 1 : 0);
  }

  k_bounds<<<1, 512, 0, stream>>>(batch, gstart);
  k_pool  <<<N_GRAPHS_C, 128, 0, stream>>>(h, gstart, gpool);
  k_head  <<<N_GRAPHS_C, 64, 0, stream>>>(gpool, Wc1, bc1, Wc2, bc2, out);
}

// Round 6
// 573.825 us; speedup vs baseline: 1.1347x; 1.1347x over previous
//
#include <hip/hip_runtime.h>

typedef float v4f __attribute__((ext_vector_type(4)));

#define N_NODES_C 50000
#define N_EDGES_C 800000
#define NF 128
#define N_GRAPHS_C 256
#define N_CLASSES_C 10

#define SCAN_CHUNK 512
#define SCAN_NB ((N_NODES_C + SCAN_CHUNK - 1) / SCAN_CHUNK)   // 98

// ---------------------------------------------------------------- CSR build
__global__ void k_deg(const int* __restrict__ dst, int* __restrict__ deg) {
  int i = blockIdx.x * blockDim.x + threadIdx.x;
  int stride = gridDim.x * blockDim.x;
  for (; i < N_EDGES_C; i += stride) atomicAdd(&deg[dst[i]], 1);
}

// stage 1: per-block sum of 512-elem chunk; also computes dinv (fused)
__global__ __launch_bounds__(256) void k_sc1(const int* __restrict__ deg,
                                             float* __restrict__ dinv,
                                             int* __restrict__ bsum) {
  __shared__ int sd[256];
  int b = blockIdx.x, t = threadIdx.x;
  int i0 = b * SCAN_CHUNK + t * 2;
  int e0 = 0, e1 = 0;
  if (i0 < N_NODES_C)     { e0 = deg[i0];     dinv[i0]     = rsqrtf((float)e0 + 1.0f); }
  if (i0 + 1 < N_NODES_C) { e1 = deg[i0 + 1]; dinv[i0 + 1] = rsqrtf((float)e1 + 1.0f); }
  sd[t] = e0 + e1;
  __syncthreads();
  for (int o = 128; o > 0; o >>= 1) {
    if (t < o) sd[t] += sd[t + o];
    __syncthreads();
  }
  if (t == 0) bsum[b] = sd[0];
}

// stage 2: exclusive scan of the 98 block sums (1 block)
__global__ __launch_bounds__(128) void k_sc2(const int* __restrict__ bsum,
                                             int* __restrict__ boff,
                                             int* __restrict__ ptr) {
  __shared__ int sd[128];
  int t = threadIdx.x;
  int v = (t < SCAN_NB) ? bsum[t] : 0;
  sd[t] = v;
  __syncthreads();
  for (int o = 1; o < 128; o <<= 1) {
    int y = (t >= o) ? sd[t - o] : 0;
    __syncthreads();
    sd[t] += y;
    __syncthreads();
  }
  if (t < SCAN_NB) boff[t] = sd[t] - v;          // exclusive
  if (t == SCAN_NB - 1) ptr[N_NODES_C] = sd[t];  // total
}

// stage 3: local exclusive scan + block offset -> csr_ptr
__global__ __launch_bounds__(256) void k_sc3(const int* __restrict__ deg,
                                             const int* __restrict__ boff,
                                             int* __restrict__ ptr) {
  __shared__ int sd[256];
  int b = blockIdx.x, t = threadIdx.x;
  int i0 = b * SCAN_CHUNK + t * 2;
  int e0 = (i0 < N_NODES_C) ? deg[i0] : 0;
  int e1 = (i0 + 1 < N_NODES_C) ? deg[i0 + 1] : 0;
  int pair = e0 + e1;
  sd[t] = pair;
  __syncthreads();
  for (int o = 1; o < 256; o <<= 1) {
    int y = (t >= o) ? sd[t - o] : 0;
    __syncthreads();
    sd[t] += y;
    __syncthreads();
  }
  int excl = boff[b] + sd[t] - pair;  // exclusive prefix for this thread's pair
  if (i0 < N_NODES_C)     ptr[i0] = excl;
  if (i0 + 1 < N_NODES_C) ptr[i0 + 1] = excl + e0;
}

__global__ void k_fill(const int* __restrict__ src, const int* __restrict__ dst,
                       const int* __restrict__ ptr, int* __restrict__ fill,
                       int* __restrict__ csr_src) {
  int i = blockIdx.x * blockDim.x + threadIdx.x;
  int stride = gridDim.x * blockDim.x;
  for (; i < N_EDGES_C; i += stride) {
    int d = dst[i];
    int pos = atomicAdd(&fill[d], 1);
    csr_src[ptr[d] + pos] = src[i];
  }
}

// ---------------------------------------------------------------- GEMM (fp32 vector)
#define TN 64
__global__ __launch_bounds__(256) void k_gemm(const float* __restrict__ A,
    const float* __restrict__ W, const float* __restrict__ bias,
    float* __restrict__ out, int n, int fuse) {
  __shared__ float Wl[64 * 128];
  __shared__ float Hl[TN * 128];
  int t = threadIdx.x;
  int oq = t & 15;
  int ng4 = (t >> 4) * 4;
  int nchunks = (n + TN - 1) / TN;
  for (int chunk = blockIdx.x; chunk < nchunks; chunk += gridDim.x) {
    int n0 = chunk * TN;
    __syncthreads();
    {
      const v4f* A4 = (const v4f*)A;
      v4f* H4 = (v4f*)Hl;
      #pragma unroll
      for (int i = 0; i < 8; ++i) {
        int idx = t + i * 256;
        int row = n0 + (idx >> 5);
        H4[idx] = (row < n) ? A4[(size_t)row * 32 + (idx & 31)] : (v4f)0.0f;
      }
    }
    v4f acc0[4], acc1[4];
    #pragma unroll
    for (int j = 0; j < 4; ++j) { acc0[j] = (v4f)0.0f; acc1[j] = (v4f)0.0f; }
    #pragma unroll 1
    for (int half = 0; half < 2; ++half) {
      int kk = half << 6;
      __syncthreads();
      {
        const v4f* W4 = (const v4f*)(W + (size_t)kk * 128);
        v4f* WL4 = (v4f*)Wl;
        #pragma unroll
        for (int i = 0; i < 8; ++i) WL4[t + i * 256] = W4[t + i * 256];
      }
      __syncthreads();
      #pragma unroll 4
      for (int k4 = 0; k4 < 16; ++k4) {
        v4f hA = *(const v4f*)&Hl[(ng4 + 0) * 128 + kk + k4 * 4];
        v4f hB = *(const v4f*)&Hl[(ng4 + 1) * 128 + kk + k4 * 4];
        v4f hC = *(const v4f*)&Hl[(ng4 + 2) * 128 + kk + k4 * 4];
        v4f hD = *(const v4f*)&Hl[(ng4 + 3) * 128 + kk + k4 * 4];
        #pragma unroll
        for (int u = 0; u < 4; ++u) {
          const float* wr = Wl + (k4 * 4 + u) * 128 + oq * 8;
          v4f w0 = *(const v4f*)wr;
          v4f w1 = *(const v4f*)(wr + 4);
          acc0[0] += hA[u] * w0; acc1[0] += hA[u] * w1;
          acc0[1] += hB[u] * w0; acc1[1] += hB[u] * w1;
          acc0[2] += hC[u] * w0; acc1[2] += hC[u] * w1;
          acc0[3] += hD[u] * w0; acc1[3] += hD[u] * w1;
        }
      }
    }
    v4f b0 = (v4f)0.0f, b1 = (v4f)0.0f;
    if (fuse) { b0 = *(const v4f*)(bias + oq * 8); b1 = *(const v4f*)(bias + oq * 8 + 4); }
    #pragma unroll
    for (int j = 0; j < 4; ++j) {
      int row = n0 + ng4 + j;
      if (row >= n) break;
      v4f r0 = acc0[j], r1 = acc1[j];
      if (fuse) {
        r0 += b0; r1 += b1;
        #pragma unroll
        for (int c = 0; c < 4; ++c) { r0[c] = fmaxf(r0[c], 0.0f); r1[c] = fmaxf(r1[c], 0.0f); }
      }
      *(v4f*)(out + (size_t)row * 128 + oq * 8) = r0;
      *(v4f*)(out + (size_t)row * 128 + oq * 8 + 4) = r1;
    }
  }
}

// ---------------------------------------------------------------- aggregation
__global__ __launch_bounds__(256) void k_agg(const float* __restrict__ hw,
    const int* __restrict__ ptr, const int* __restrict__ csr_src,
    const float* __restrict__ dinv, const float* __restrict__ bias,
    float* __restrict__ h, int residual) {
  int node = blockIdx.x * 4 + (threadIdx.x >> 6);
  int lane = threadIdx.x & 63;
  if (node >= N_NODES_C) return;
  const float2* hw2 = (const float2*)hw;
  int beg = ptr[node], end = ptr[node + 1];
  float ax = 0.f, ay = 0.f;
  int e = beg;
  for (; e + 4 <= end; e += 4) {
    int s0 = csr_src[e], s1 = csr_src[e + 1], s2 = csr_src[e + 2], s3 = csr_src[e + 3];
    float d0 = dinv[s0], d1 = dinv[s1], d2 = dinv[s2], d3 = dinv[s3];
    float2 v0 = hw2[s0 * 64 + lane];
    float2 v1 = hw2[s1 * 64 + lane];
    float2 v2 = hw2[s2 * 64 + lane];
    float2 v3 = hw2[s3 * 64 + lane];
    ax += d0 * v0.x + d1 * v1.x + d2 * v2.x + d3 * v3.x;
    ay += d0 * v0.y + d1 * v1.y + d2 * v2.y + d3 * v3.y;
  }
  for (; e < end; ++e) {
    int s = csr_src[e];
    float d = dinv[s];
    float2 v = hw2[s * 64 + lane];
    ax += d * v.x; ay += d * v.y;
  }
  float di = dinv[node];
  float2 self = hw2[node * 64 + lane];
  float2 b = ((const float2*)bias)[lane];
  float vx = fmaxf(di * ax + di * di * self.x + b.x, 0.0f);
  float vy = fmaxf(di * ay + di * di * self.y + b.y, 0.0f);
  float2* h2 = (float2*)h;
  if (residual) {
    float2 old = h2[node * 64 + lane];
    vx += old.x; vy += old.y;
  }
  h2[node * 64 + lane] = make_float2(vx, vy);
}

// ---------------------------------------------------------------- pooling + head
__global__ void k_bounds(const int* __restrict__ batch, int* __restrict__ gstart) {
  int g = threadIdx.x;
  if (g > N_GRAPHS_C) return;
  int lo = 0, hi = N_NODES_C;
  while (lo < hi) {
    int mid = (lo + hi) >> 1;
    if (batch[mid] < g) lo = mid + 1; else hi = mid;
  }
  gstart[g] = lo;
}

__global__ void k_pool(const float* __restrict__ h, const int* __restrict__ gstart,
                       float* __restrict__ gpool) {
  int g = blockIdx.x;
  int f = threadIdx.x;
  int beg = gstart[g], end = gstart[g + 1];
  float acc = 0.f;
  for (int n2 = beg; n2 < end; ++n2) acc += h[(size_t)n2 * NF + f];
  float cnt = (float)(end - beg);
  gpool[g * NF + f] = acc / fmaxf(cnt, 1.0f);
}

__global__ void k_head(const float* __restrict__ gpool, const float* __restrict__ Wc1,
                       const float* __restrict__ bc1, const float* __restrict__ Wc2,
                       const float* __restrict__ bc2, float* __restrict__ out) {
  __shared__ float gv[128];
  __shared__ float hid[64];
  int g = blockIdx.x, t = threadIdx.x;
  gv[t] = gpool[g * 128 + t];
  gv[t + 64] = gpool[g * 128 + t + 64];
  __syncthreads();
  float s = bc1[t];
  #pragma unroll 8
  for (int k = 0; k < 128; ++k) s += gv[k] * Wc1[k * 64 + t];
  hid[t] = fmaxf(s, 0.0f);
  __syncthreads();
  if (t < N_CLASSES_C) {
    float o = bc2[t];
    #pragma unroll
    for (int k = 0; k < 64; ++k) o += hid[k] * Wc2[k * 10 + t];
    out[g * 10 + t] = o;
  }
}

// ---------------------------------------------------------------- launch
extern "C" void kernel_launch(void* const* d_in, const int* in_sizes, int n_in,
                              void* d_out, int out_size, void* d_ws, size_t ws_size,
                              hipStream_t stream) {
  const float* x    = (const float*)d_in[0];
  const int*   ei   = (const int*)d_in[1];
  const int*   batch= (const int*)d_in[2];
  const float* W_in = (const float*)d_in[3];
  const float* b_in = (const float*)d_in[4];
  const float* Ws   = (const float*)d_in[5];
  const float* bs   = (const float*)d_in[6];
  const float* Wc1  = (const float*)d_in[7];
  const float* bc1  = (const float*)d_in[8];
  const float* Wc2  = (const float*)d_in[9];
  const float* bc2  = (const float*)d_in[10];
  float* out = (float*)d_out;

  const int* src = ei;
  const int* dst = ei + N_EDGES_C;

  char* ws = (char*)d_ws;
  size_t off = 0;
  auto alloc = [&](size_t bytes) -> void* {
    void* p = ws + off;
    off += (bytes + 255) & ~(size_t)255;
    return p;
  };
  int*   deg     = (int*)alloc(N_NODES_C * 4);
  int*   fill    = (int*)alloc(N_NODES_C * 4);
  int*   csr_ptr = (int*)alloc((N_NODES_C + 1) * 4);
  int*   csr_src = (int*)alloc((size_t)N_EDGES_C * 4);
  float* dinv    = (float*)alloc(N_NODES_C * 4);
  int*   gstart  = (int*)alloc((N_GRAPHS_C + 1) * 4);
  int*   bsum    = (int*)alloc(SCAN_NB * 4);
  int*   boff    = (int*)alloc(SCAN_NB * 4);
  float* h       = (float*)alloc((size_t)N_NODES_C * NF * 4);
  float* hw      = (float*)alloc((size_t)N_NODES_C * NF * 4);
  float* gpool   = (float*)alloc((size_t)N_GRAPHS_C * NF * 4);
  (void)ws_size; (void)in_sizes; (void)n_in; (void)out_size;

  hipMemsetAsync(deg, 0, N_NODES_C * 4, stream);
  hipMemsetAsync(fill, 0, N_NODES_C * 4, stream);

  k_deg<<<1024, 256, 0, stream>>>(dst, deg);
  k_sc1<<<SCAN_NB, 256, 0, stream>>>(deg, dinv, bsum);
  k_sc2<<<1, 128, 0, stream>>>(bsum, boff, csr_ptr);
  k_sc3<<<SCAN_NB, 256, 0, stream>>>(deg, boff, csr_ptr);
  k_fill<<<1024, 256, 0, stream>>>(src, dst, csr_ptr, fill, csr_src);

  k_gemm<<<512, 256, 0, stream>>>(x, W_in, b_in, h, N_NODES_C, 1);

  for (int L = 0; L < 3; ++L) {
    k_gemm<<<512, 256, 0, stream>>>(h, Ws + (size_t)L * NF * NF, nullptr, hw, N_NODES_C, 0);
    k_agg <<<(N_NODES_C + 3) / 4, 256, 0, stream>>>(hw, csr_ptr, csr_src, dinv,
                                                    bs + (size_t)L * NF, h, (L > 0) ? 1 : 0);
  }

  k_bounds<<<1, 512, 0, stream>>>(batch, gstart);
  k_pool  <<<N_GRAPHS_C, 128, 0, stream>>>(h, gstart, gpool);
  k_head  <<<N_GRAPHS_C, 64, 0, stream>>>(gpool, Wc1, bc1, Wc2, bc2, out);
}

// Round 8
// 557.402 us; speedup vs baseline: 1.1681x; 1.0295x over previous
//
#include <hip/hip_runtime.h>

typedef float v4f __attribute__((ext_vector_type(4)));

#define N_NODES_C 50000
#define N_EDGES_C 800000
#define NF 128
#define N_GRAPHS_C 256
#define N_CLASSES_C 10

#define SCAN_CHUNK 512
#define SCAN_NB ((N_NODES_C + SCAN_CHUNK - 1) / SCAN_CHUNK)   // 98

// ---------------------------------------------------------------- CSR build
__global__ void k_deg(const int* __restrict__ dst, int* __restrict__ deg) {
  int i = blockIdx.x * blockDim.x + threadIdx.x;
  int stride = gridDim.x * blockDim.x;
  for (; i < N_EDGES_C; i += stride) atomicAdd(&deg[dst[i]], 1);
}

__global__ __launch_bounds__(256) void k_sc1(const int* __restrict__ deg,
                                             float* __restrict__ dinv,
                                             int* __restrict__ bsum) {
  __shared__ int sd[256];
  int b = blockIdx.x, t = threadIdx.x;
  int i0 = b * SCAN_CHUNK + t * 2;
  int e0 = 0, e1 = 0;
  if (i0 < N_NODES_C)     { e0 = deg[i0];     dinv[i0]     = rsqrtf((float)e0 + 1.0f); }
  if (i0 + 1 < N_NODES_C) { e1 = deg[i0 + 1]; dinv[i0 + 1] = rsqrtf((float)e1 + 1.0f); }
  sd[t] = e0 + e1;
  __syncthreads();
  for (int o = 128; o > 0; o >>= 1) {
    if (t < o) sd[t] += sd[t + o];
    __syncthreads();
  }
  if (t == 0) bsum[b] = sd[0];
}

__global__ __launch_bounds__(128) void k_sc2(const int* __restrict__ bsum,
                                             int* __restrict__ boff,
                                             int* __restrict__ ptr) {
  __shared__ int sd[128];
  int t = threadIdx.x;
  int v = (t < SCAN_NB) ? bsum[t] : 0;
  sd[t] = v;
  __syncthreads();
  for (int o = 1; o < 128; o <<= 1) {
    int y = (t >= o) ? sd[t - o] : 0;
    __syncthreads();
    sd[t] += y;
    __syncthreads();
  }
  if (t < SCAN_NB) boff[t] = sd[t] - v;
  if (t == SCAN_NB - 1) ptr[N_NODES_C] = sd[t];
}

__global__ __launch_bounds__(256) void k_sc3(const int* __restrict__ deg,
                                             const int* __restrict__ boff,
                                             int* __restrict__ ptr) {
  __shared__ int sd[256];
  int b = blockIdx.x, t = threadIdx.x;
  int i0 = b * SCAN_CHUNK + t * 2;
  int e0 = (i0 < N_NODES_C) ? deg[i0] : 0;
  int e1 = (i0 + 1 < N_NODES_C) ? deg[i0 + 1] : 0;
  int pair = e0 + e1;
  sd[t] = pair;
  __syncthreads();
  for (int o = 1; o < 256; o <<= 1) {
    int y = (t >= o) ? sd[t - o] : 0;
    __syncthreads();
    sd[t] += y;
    __syncthreads();
  }
  int excl = boff[b] + sd[t] - pair;
  if (i0 < N_NODES_C)     ptr[i0] = excl;
  if (i0 + 1 < N_NODES_C) ptr[i0 + 1] = excl + e0;
}

__global__ void k_fill(const int* __restrict__ src, const int* __restrict__ dst,
                       const int* __restrict__ ptr, int* __restrict__ fill,
                       int* __restrict__ csr_src) {
  int i = blockIdx.x * blockDim.x + threadIdx.x;
  int stride = gridDim.x * blockDim.x;
  for (; i < N_EDGES_C; i += stride) {
    int d = dst[i];
    int pos = atomicAdd(&fill[d], 1);
    csr_src[ptr[d] + pos] = src[i];
  }
}

// ---------------------------------------------------------------- GEMM (fp32 vector, LDS de-conflicted)
// H tile: rows padded to 33 float4 (132 floats) -> wave's 4 row-addrs hit
// disjoint bank-quads (conflict-free). W tile: column skew cf'=cf+(cf>>3),
// row stride 35 float4 -> 16 oq-addrs cover each bank-quad exactly 2x (2-way, free).
#define TN 64
#define HS4 33
#define WS4 35
__global__ __launch_bounds__(256) void k_gemm(const float* __restrict__ A,
    const float* __restrict__ W, const float* __restrict__ bias,
    float* __restrict__ out, int n, int fuse) {
  __shared__ v4f Hl4[TN * HS4];   // 33792 B
  __shared__ v4f Wl4[64 * WS4];   // 35840 B
  int t = threadIdx.x;
  int oq = t & 15;          // output col group: cols oq*8 .. oq*8+7
  int ng = t >> 4;          // 0..15: rows ng, ng+16, ng+32, ng+48
  int woff0 = 2 * oq + ((2 * oq) >> 3);   // skewed W f4 offset
  int nchunks = (n + TN - 1) / TN;
  for (int chunk = blockIdx.x; chunk < nchunks; chunk += gridDim.x) {
    int n0 = chunk * TN;
    __syncthreads();
    {
      const v4f* A4 = (const v4f*)A;
      #pragma unroll
      for (int i = 0; i < 8; ++i) {
        int idx = t + i * 256;              // 0..2047
        int row = idx >> 5, col = idx & 31;
        Hl4[row * HS4 + col] =
            (n0 + row < n) ? A4[(size_t)(n0 + row) * 32 + col] : (v4f)0.0f;
      }
    }
    v4f acc0[4], acc1[4];
    #pragma unroll
    for (int j = 0; j < 4; ++j) { acc0[j] = (v4f)0.0f; acc1[j] = (v4f)0.0f; }
    #pragma unroll 1
    for (int half = 0; half < 2; ++half) {
      int kk4 = half << 4;    // f4 col offset into H (k dim)
      __syncthreads();
      {
        const v4f* W4 = (const v4f*)(W + (size_t)(half << 6) * 128);
        #pragma unroll
        for (int i = 0; i < 8; ++i) {
          int idx = t + i * 256;            // 0..2047
          int r = idx >> 5, cf = idx & 31;
          Wl4[r * WS4 + cf + (cf >> 3)] = W4[r * 32 + cf];
        }
      }
      __syncthreads();
      #pragma unroll 4
      for (int k4 = 0; k4 < 16; ++k4) {
        v4f hA = Hl4[(ng +  0) * HS4 + kk4 + k4];
        v4f hB = Hl4[(ng + 16) * HS4 + kk4 + k4];
        v4f hC = Hl4[(ng + 32) * HS4 + kk4 + k4];
        v4f hD = Hl4[(ng + 48) * HS4 + kk4 + k4];
        #pragma unroll
        for (int u = 0; u < 4; ++u) {
          int rr = k4 * 4 + u;
          v4f w0 = Wl4[rr * WS4 + woff0];
          v4f w1 = Wl4[rr * WS4 + woff0 + 1];
          acc0[0] += hA[u] * w0; acc1[0] += hA[u] * w1;
          acc0[1] += hB[u] * w0; acc1[1] += hB[u] * w1;
          acc0[2] += hC[u] * w0; acc1[2] += hC[u] * w1;
          acc0[3] += hD[u] * w0; acc1[3] += hD[u] * w1;
        }
      }
    }
    v4f b0 = (v4f)0.0f, b1 = (v4f)0.0f;
    if (fuse) { b0 = ((const v4f*)bias)[oq * 2]; b1 = ((const v4f*)bias)[oq * 2 + 1]; }
    #pragma unroll
    for (int j = 0; j < 4; ++j) {
      int row = n0 + ng + 16 * j;
      if (row < n) {
        v4f r0 = acc0[j], r1 = acc1[j];
        if (fuse) {
          r0 += b0; r1 += b1;
          #pragma unroll
          for (int c = 0; c < 4; ++c) { r0[c] = fmaxf(r0[c], 0.0f); r1[c] = fmaxf(r1[c], 0.0f); }
        }
        *(v4f*)(out + (size_t)row * 128 + oq * 8) = r0;
        *(v4f*)(out + (size_t)row * 128 + oq * 8 + 4) = r1;
      }
    }
  }
}

// ---------------------------------------------------------------- aggregation (float4, 2 rows/instr)
__global__ __launch_bounds__(256) void k_agg(const float* __restrict__ hw,
    const int* __restrict__ ptr, const int* __restrict__ csr_src,
    const float* __restrict__ dinv, const float* __restrict__ bias,
    float* __restrict__ h, int residual) {
  int node = blockIdx.x * 4 + (threadIdx.x >> 6);
  int lane = threadIdx.x & 63;
  int half = lane >> 5;     // half-wave owns alternating edges
  int c4 = lane & 31;       // float4 column of the 128-float row
  if (node >= N_NODES_C) return;
  const v4f* hw4 = (const v4f*)hw;
  int beg = ptr[node], end = ptr[node + 1];
  v4f acc = (v4f)0.0f;
  int e = beg;
  for (; e + 8 <= end; e += 8) {
    int i0 = e + half, i1 = i0 + 2, i2 = i0 + 4, i3 = i0 + 6;
    int s0 = csr_src[i0], s1 = csr_src[i1], s2 = csr_src[i2], s3 = csr_src[i3];
    float d0 = dinv[s0], d1 = dinv[s1], d2 = dinv[s2], d3 = dinv[s3];
    v4f v0 = hw4[(size_t)s0 * 32 + c4];
    v4f v1 = hw4[(size_t)s1 * 32 + c4];
    v4f v2 = hw4[(size_t)s2 * 32 + c4];
    v4f v3 = hw4[(size_t)s3 * 32 + c4];
    acc += d0 * v0; acc += d1 * v1; acc += d2 * v2; acc += d3 * v3;
  }
  for (; e < end; e += 2) {
    int idx = e + half;
    if (idx < end) {
      int s = csr_src[idx];
      acc += dinv[s] * hw4[(size_t)s * 32 + c4];
    }
  }
  // combine the two half-wave partial sums (lane i <-> lane i^32)
  v4f tot;
  #pragma unroll
  for (int c = 0; c < 4; ++c) tot[c] = acc[c] + __shfl_xor(acc[c], 32);

  float di = dinv[node];
  v4f self = hw4[(size_t)node * 32 + c4];
  v4f b = ((const v4f*)bias)[c4];
  v4f r = di * tot + (di * di) * self + b;
  #pragma unroll
  for (int c = 0; c < 4; ++c) r[c] = fmaxf(r[c], 0.0f);
  v4f* h4 = (v4f*)h;
  if (residual) r += h4[(size_t)node * 32 + c4];   // read before the store below (in-wave order)
  if (half == 0) h4[(size_t)node * 32 + c4] = r;
}

// ---------------------------------------------------------------- pooling + head
__global__ void k_bounds(const int* __restrict__ batch, int* __restrict__ gstart) {
  int g = threadIdx.x;
  if (g > N_GRAPHS_C) return;
  int lo = 0, hi = N_NODES_C;
  while (lo < hi) {
    int mid = (lo + hi) >> 1;
    if (batch[mid] < g) lo = mid + 1; else hi = mid;
  }
  gstart[g] = lo;
}

__global__ void k_pool(const float* __restrict__ h, const int* __restrict__ gstart,
                       float* __restrict__ gpool) {
  int g = blockIdx.x;
  int f = threadIdx.x;
  int beg = gstart[g], end = gstart[g + 1];
  float acc = 0.f;
  for (int n2 = beg; n2 < end; ++n2) acc += h[(size_t)n2 * NF + f];
  float cnt = (float)(end - beg);
  gpool[g * NF + f] = acc / fmaxf(cnt, 1.0f);
}

__global__ void k_head(const float* __restrict__ gpool, const float* __restrict__ Wc1,
                       const float* __restrict__ bc1, const float* __restrict__ Wc2,
                       const float* __restrict__ bc2, float* __restrict__ out) {
  __shared__ float gv[128];
  __shared__ float hid[64];
  int g = blockIdx.x, t = threadIdx.x;
  gv[t] = gpool[g * 128 + t];
  gv[t + 64] = gpool[g * 128 + t + 64];
  __syncthreads();
  float s = bc1[t];
  #pragma unroll 8
  for (int k = 0; k < 128; ++k) s += gv[k] * Wc1[k * 64 + t];
  hid[t] = fmaxf(s, 0.0f);
  __syncthreads();
  if (t < N_CLASSES_C) {
    float o = bc2[t];
    #pragma unroll
    for (int k = 0; k < 64; ++k) o += hid[k] * Wc2[k * 10 + t];
    out[g * 10 + t] = o;
  }
}

// ---------------------------------------------------------------- launch
extern "C" void kernel_launch(void* const* d_in, const int* in_sizes, int n_in,
                              void* d_out, int out_size, void* d_ws, size_t ws_size,
                              hipStream_t stream) {
  const float* x    = (const float*)d_in[0];
  const int*   ei   = (const int*)d_in[1];
  const int*   batch= (const int*)d_in[2];
  const float* W_in = (const float*)d_in[3];
  const float* b_in = (const float*)d_in[4];
  const float* Ws   = (const float*)d_in[5];
  const float* bs   = (const float*)d_in[6];
  const float* Wc1  = (const float*)d_in[7];
  const float* bc1  = (const float*)d_in[8];
  const float* Wc2  = (const float*)d_in[9];
  const float* bc2  = (const float*)d_in[10];
  float* out = (float*)d_out;

  const int* src = ei;
  const int* dst = ei + N_EDGES_C;

  char* ws = (char*)d_ws;
  size_t off = 0;
  auto alloc = [&](size_t bytes) -> void* {
    void* p = ws + off;
    off += (bytes + 255) & ~(size_t)255;
    return p;
  };
  int*   deg     = (int*)alloc(N_NODES_C * 4);
  int*   fill    = (int*)alloc(N_NODES_C * 4);
  int*   csr_ptr = (int*)alloc((N_NODES_C + 1) * 4);
  int*   csr_src = (int*)alloc((size_t)N_EDGES_C * 4);
  float* dinv    = (float*)alloc(N_NODES_C * 4);
  int*   gstart  = (int*)alloc((N_GRAPHS_C + 1) * 4);
  int*   bsum    = (int*)alloc(SCAN_NB * 4);
  int*   boff    = (int*)alloc(SCAN_NB * 4);
  float* h       = (float*)alloc((size_t)N_NODES_C * NF * 4);
  float* hw      = (float*)alloc((size_t)N_NODES_C * NF * 4);
  float* gpool   = (float*)alloc((size_t)N_GRAPHS_C * NF * 4);
  (void)ws_size; (void)in_sizes; (void)n_in; (void)out_size;

  hipMemsetAsync(deg, 0, N_NODES_C * 4, stream);
  hipMemsetAsync(fill, 0, N_NODES_C * 4, stream);

  k_deg<<<1024, 256, 0, stream>>>(dst, deg);
  k_sc1<<<SCAN_NB, 256, 0, stream>>>(deg, dinv, bsum);
  k_sc2<<<1, 128, 0, stream>>>(bsum, boff, csr_ptr);
  k_sc3<<<SCAN_NB, 256, 0, stream>>>(deg, boff, csr_ptr);
  k_fill<<<1024, 256, 0, stream>>>(src, dst, csr_ptr, fill, csr_src);

  k_gemm<<<512, 256, 0, stream>>>(x, W_in, b_in, h, N_NODES_C, 1);

  for (int L = 0; L < 3; ++L) {
    k_gemm<<<512, 256, 0, stream>>>(h, Ws + (size_t)L * NF * NF, nullptr, hw, N_NODES_C, 0);
    k_agg <<<(N_NODES_C + 3) / 4, 256, 0, stream>>>(hw, csr_ptr, csr_src, dinv,
                                                    bs + (size_t)L * NF, h, (L > 0) ? 1 : 0);
  }

  k_bounds<<<1, 512, 0, stream>>>(batch, gstart);
  k_pool  <<<N_GRAPHS_C, 128, 0, stream>>>(h, gstart, gpool);
  k_head  <<<N_GRAPHS_C, 64, 0, stream>>>(gpool, Wc1, bc1, Wc2, bc2, out);
}